// Round 20
// baseline (587.710 us; speedup 1.0000x reference)
//
#include <hip/hip_runtime.h>
#include <math.h>

namespace {

constexpr int Bn=2, CIc=16, COc=16, Hc=256, Wc=256, HIDc=64, C5c=320;
constexpr int SPc = 4096;               // 64*64
constexpr float EPSc = 1e-5f;

// ---- 4x4 mean downsample: x (B,16,256,256) -> xd (B,16,64,64) ----
__global__ void k_down(const float* __restrict__ x, float* __restrict__ xd){
  int idx = blockIdx.x*blockDim.x + threadIdx.x;
  if (idx >= Bn*CIc*SPc) return;
  int q = idx & 63, p = (idx>>6)&63, c = idx>>12;
  const float* xp = x + ((size_t)c*Hc + p*4)*Wc + q*4;
  float s = 0.f;
  #pragma unroll
  for(int dy=0; dy<4; dy++)
    #pragma unroll
    for(int dx=0; dx<4; dx++) s += xp[dy*Wc+dx];
  xd[idx] = s * (1.f/16.f);
}

// ---- conv0 3x3 pad1 (16->64) + scalar PReLU; h spatial-major [b][s][64] ----
// idx = (b, s, co): lane = co -> contiguous 256B writes; xd reads wave-uniform.
__global__ void k_conv0(const float* __restrict__ xd, const float* __restrict__ w,
                        const float* __restrict__ bias, const float* __restrict__ a0,
                        float* __restrict__ h){
  int idx = blockIdx.x*blockDim.x + threadIdx.x;
  int co = idx & 63, s = (idx>>6) & (SPc-1), b = idx>>18;
  int q = s & 63, p = s >> 6;
  float acc = bias[co];
  for(int ci=0; ci<CIc; ci++){
    const float* xp = xd + (size_t)(b*CIc+ci)*SPc;
    const float* wp = w + (co*CIc+ci)*9;
    #pragma unroll
    for(int u=0; u<3; u++){
      int pp = p+u-1; if((unsigned)pp >= 64u) continue;
      #pragma unroll
      for(int v=0; v<3; v++){
        int qq = q+v-1; if((unsigned)qq >= 64u) continue;
        acc = fmaf(xp[pp*64+qq], wp[u*3+v], acc);
      }
    }
  }
  float a = a0[0];
  h[idx] = acc >= 0.f ? acc : a*acc;
}

// ---- fused 1x1 conv 64->320 + BN1 stat partials; h spatial-major input ----
__global__ void k_c1(const float* __restrict__ h, const float* __restrict__ w,
                     const float* __restrict__ bias, float* __restrict__ t1,
                     float* __restrict__ pacc){
  __shared__ float lh[64*65];     // [c][s] padded (+65 stride)
  int og = blockIdx.x, sj = blockIdx.y, b = blockIdx.z;
  int tid = threadIdx.x;
  // stage 16KB contiguous: t = (s, cq); transpose into lh
  for(int t = tid; t < 1024; t += 256){
    int s = t>>4, cq = t&15;
    float4 v = *(const float4*)(h + ((size_t)(b*SPc + sj*64 + s))*64 + cq*4);
    lh[(cq*4+0)*65 + s] = v.x;
    lh[(cq*4+1)*65 + s] = v.y;
    lh[(cq*4+2)*65 + s] = v.z;
    lh[(cq*4+3)*65 + s] = v.w;
  }
  __syncthreads();
  int osub = tid>>6, s = tid&63;
  int ob = og*40 + osub*10;
  float acc[10];
  #pragma unroll
  for(int j=0;j<10;j++) acc[j] = bias[ob+j];
  for(int c=0;c<64;c++){
    float hv = lh[c*65+s];
    #pragma unroll
    for(int j=0;j<10;j++) acc[j] = fmaf(hv, w[(ob+j)*64 + c], acc[j]);
  }
  #pragma unroll
  for(int j=0;j<10;j++){
    int o = ob+j;
    t1[(size_t)(b*320+o)*SPc + sj*64 + s] = acc[j];
    float sm = acc[j], sq = acc[j]*acc[j];
    #pragma unroll
    for(int d=1; d<64; d<<=1){ sm += __shfl_xor(sm,d); sq += __shfl_xor(sq,d); }
    if(s==0){
      pacc[o*128 + b*64 + sj]         = sm;   // P=128
      pacc[40960 + o*128 + b*64 + sj] = sq;   // CP = 320*128
    }
  }
}

// ---- finalize: partials -> fused BN scale/shift A,B ----
__global__ void k_fin(const float* __restrict__ pacc, int P, float invN,
                      const float* __restrict__ g, const float* __restrict__ bb,
                      float* __restrict__ A, float* __restrict__ B){
  __shared__ double sh[256], sh2[256];
  int c = blockIdx.x, C = gridDim.x, tid = threadIdx.x;
  double s=0.0, s2=0.0;
  for(int p=tid; p<P; p+=256){
    s  += (double)pacc[c*P+p];
    s2 += (double)pacc[C*P + c*P + p];
  }
  sh[tid]=s; sh2[tid]=s2; __syncthreads();
  for(int off=128; off>0; off>>=1){
    if(tid<off){ sh[tid]+=sh[tid+off]; sh2[tid]+=sh2[tid+off]; }
    __syncthreads();
  }
  if(tid==0){
    float m = (float)(sh[0]*(double)invN);
    float v = (float)(sh2[0]*(double)invN) - m*m;
    float r = rsqrtf(v + EPSc);
    float gc = g[c];
    A[c] = gc*r;
    B[c] = bb[c] - m*gc*r;
  }
}

// ---- depthwise 3x3; BN1 finalized in prologue; BN2 partials out ----
__global__ void k_dw_s(const float* __restrict__ t1, const float* __restrict__ w,
                       const float* __restrict__ bias, const float* __restrict__ g1,
                       const float* __restrict__ bb1, const float* __restrict__ ap,
                       const float* __restrict__ pin, float* __restrict__ t2,
                       float* __restrict__ pout){
  int tid = threadIdx.x;
  int idx = blockIdx.x*256 + tid;
  int q = idx&63, p=(idx>>6)&63, c=(idx>>12)%C5c, b=idx/(C5c*SPc);
  __shared__ float sAB[2];
  __shared__ float ws4[4];
  {
    float v = (tid<128) ? pin[c*128 + tid] : pin[40960 + c*128 + (tid-128)];
    #pragma unroll
    for(int d=1; d<64; d<<=1) v += __shfl_xor(v, d);
    int wv = tid>>6, ln = tid&63;
    if(ln==0) ws4[wv] = v;
    __syncthreads();
    if(tid==0){
      float S = ws4[0]+ws4[1], Q = ws4[2]+ws4[3];
      float m = S*(1.f/8192.f);
      float var = Q*(1.f/8192.f) - m*m;
      float r = rsqrtf(var + EPSc);
      float gc = g1[c];
      sAB[0] = gc*r; sAB[1] = bb1[c] - m*gc*r;
    }
    __syncthreads();
  }
  float a1 = sAB[0], b1 = sAB[1], al = ap[0];
  const float* ip = t1 + (size_t)(b*C5c+c)*SPc;
  const float* wp = w + c*9;
  float acc = bias[c];
  #pragma unroll
  for(int u=0; u<3; u++){
    int pp = p+u-1; if((unsigned)pp >= 64u) continue;
    #pragma unroll
    for(int v=0; v<3; v++){
      int qq = q+v-1; if((unsigned)qq >= 64u) continue;
      float y = fmaf(ip[pp*64+qq], a1, b1);
      y = y >= 0.f ? y : al*y;
      acc = fmaf(y, wp[u*3+v], acc);
    }
  }
  t2[idx] = acc;
  float sm = acc, sq = acc*acc;
  #pragma unroll
  for(int d=1; d<64; d<<=1){ sm += __shfl_xor(sm,d); sq += __shfl_xor(sq,d); }
  __shared__ float sred[8];
  int wv = tid>>6, ln = tid&63;
  if(ln==0){ sred[wv]=sm; sred[4+wv]=sq; }
  __syncthreads();
  if(tid==0){
    float S = ((sred[0]+sred[1])+(sred[2]+sred[3]));
    float Q = ((sred[4]+sred[5])+(sred[6]+sred[7]));
    int j = blockIdx.x & 15;
    pout[c*32 + b*16 + j]         = S;   // P=32
    pout[10240 + c*32 + b*16 + j] = Q;   // CP = 320*32
  }
}

// ---- full-K 1x1 conv 320->64; BN2 in prologue; ts spatial-major out ----
__global__ void k_c3f(const float* __restrict__ t2, const float* __restrict__ w,
                      const float* __restrict__ bias, const float* __restrict__ g2,
                      const float* __restrict__ bb2, const float* __restrict__ ap,
                      const float* __restrict__ pin, float* __restrict__ ts,
                      float* __restrict__ pout){
  __shared__ float sA[320], sB[320];
  __shared__ float li[320*16];    // 20 KB
  int sjf = blockIdx.x, b = blockIdx.y;
  int tid = threadIdx.x;
  for(int c = tid; c < 320; c += 256){
    const float4* ps = (const float4*)(pin + c*32);
    const float4* pq = (const float4*)(pin + 10240 + c*32);
    float S=0.f, Q=0.f;
    #pragma unroll
    for(int j=0;j<8;j++){ float4 a = ps[j]; S += ((a.x+a.y)+(a.z+a.w)); }
    #pragma unroll
    for(int j=0;j<8;j++){ float4 a = pq[j]; Q += ((a.x+a.y)+(a.z+a.w)); }
    float m = S*(1.f/8192.f);
    float var = Q*(1.f/8192.f) - m*m;
    float r = rsqrtf(var + EPSc);
    float gc = g2[c];
    sA[c] = gc*r; sB[c] = bb2[c] - m*gc*r;
  }
  __syncthreads();
  float al = ap[0];
  for(int t = tid; t < 1280; t += 256){
    int c = t>>2, k4 = t&3;
    float4 v = *(const float4*)(t2 + (size_t)(b*C5c+c)*SPc + sjf*16 + k4*4);
    float a1 = sA[c], b1 = sB[c];
    float4 y;
    y.x = fmaf(v.x, a1, b1); y.x = y.x>=0.f ? y.x : al*y.x;
    y.y = fmaf(v.y, a1, b1); y.y = y.y>=0.f ? y.y : al*y.y;
    y.z = fmaf(v.z, a1, b1); y.z = y.z>=0.f ? y.z : al*y.z;
    y.w = fmaf(v.w, a1, b1); y.w = y.w>=0.f ? y.w : al*y.w;
    *(float4*)(&li[c*16 + k4*4]) = y;
  }
  __syncthreads();
  int og = tid>>4, s = tid&15;
  float acc[4];
  #pragma unroll
  for(int j=0;j<4;j++) acc[j] = bias[og*4+j];
  const float* wb = w + (size_t)(og*4)*C5c;
  for(int c=0; c<320; c++){
    float hv = li[c*16 + s];
    #pragma unroll
    for(int j=0;j<4;j++)
      acc[j] = fmaf(hv, wb[j*C5c + c], acc[j]);
  }
  // spatial-major ts write: one float4 per thread
  float4 o4 = make_float4(acc[0], acc[1], acc[2], acc[3]);
  *(float4*)(ts + ((size_t)(b*SPc + sjf*16 + s))*64 + og*4) = o4;
  #pragma unroll
  for(int j=0;j<4;j++){
    int o = og*4+j;
    float sm = acc[j], sq = acc[j]*acc[j];
    #pragma unroll
    for(int d=1; d<16; d<<=1){ sm += __shfl_xor(sm,d); sq += __shfl_xor(sq,d); }
    if(s==0){
      pout[o*512 + b*256 + sjf]         = sm;  // P=512
      pout[32768 + o*512 + b*256 + sjf] = sq;  // CP = 64*512
    }
  }
}

// ---- BN3 (A,B precomputed by k_fin) + PReLU3 + residual add into h ----
// spatial-major ts and h: fully contiguous
__global__ void k_addres(const float* __restrict__ ts, float* __restrict__ h,
                         const float* __restrict__ ap, const float* __restrict__ A,
                         const float* __restrict__ B){
  int idx = blockIdx.x*256 + threadIdx.x;
  int c = idx & 63;
  float y = fmaf(ts[idx], A[c], B[c]);
  float al = ap[0];
  y = y >= 0.f ? y : al*y;
  h[idx] += y;
}

// ---- head 1x1 conv (64->512), h spatial-major (float4 reads), gvol out ----
__global__ void k_head_t(const float* __restrict__ h, const float* __restrict__ w,
                         const float* __restrict__ bias, float* __restrict__ gv){
  __shared__ float sb0[64*65], sb1[64*65];
  int bid = blockIdx.x;            // (b*16 + o)*16 + ci
  int ci = bid & 15, o = (bid>>4) & 15, b = bid >> 8;
  int c0 = (o*16 + ci)*2, c1 = c0 + 1;
  const float* hp0 = h + (size_t)b*SPc*64;
  const float* w0 = w + (size_t)c0*HIDc;
  const float* w1 = w + (size_t)c1*HIDc;
  float b0 = bias[c0], b1 = bias[c1];
  int tid = threadIdx.x;
  for(int j=0; j<16; j++){
    int s = tid + j*256;           // s = p*64 + q
    float a0 = b0, a1 = b1;
    const float* hs = hp0 + (size_t)s*64;
    #pragma unroll
    for(int kq=0; kq<16; kq++){
      float4 hv = *(const float4*)(hs + kq*4);
      a0 = fmaf(hv.x, w0[kq*4+0], a0); a1 = fmaf(hv.x, w1[kq*4+0], a1);
      a0 = fmaf(hv.y, w0[kq*4+1], a0); a1 = fmaf(hv.y, w1[kq*4+1], a1);
      a0 = fmaf(hv.z, w0[kq*4+2], a0); a1 = fmaf(hv.z, w1[kq*4+2], a1);
      a0 = fmaf(hv.w, w0[kq*4+3], a0); a1 = fmaf(hv.w, w1[kq*4+3], a1);
    }
    int pad = s + (s>>6);
    sb0[pad] = a0; sb1[pad] = a1;
  }
  __syncthreads();
  float* gb = gv + (size_t)b*(64*16*2048);
  for(int j=0; j<16; j++){
    int t = tid + j*256;
    int q = t>>6, p = t&63;
    size_t base = ((size_t)(q*16 + ci))*2048 + (size_t)o*64 + p;
    gb[base]        = sb0[p*65 + q];   // k=0 weight plane
    gb[base + 1024] = sb1[p*65 + q];   // k=1 bias plane
  }
}

// ---- slice v4: 17-col segments (x0 block-uniform), 1 row/block, 320 thr ----
__global__ void k_slice(const float* __restrict__ x, const float* __restrict__ gv,
                        float* __restrict__ outp, float* __restrict__ pacc){
  __shared__ float lds[8320];     // 4160 float2
  int xseg = blockIdx.x, hp = blockIdx.y, b = blockIdx.z;
  int tid = threadIdx.x;
  const float* gb = gv + (size_t)b*(64*16*2048);
  int y0 = (hp*63)/255;
  int y1 = min(y0+1, 63);
  float fy = hp*(63.f/255.f) - (float)y0;

  if(tid < 128){
    int half = tid & 1, o = (tid>>1)&15, k = (tid>>5)&1, cix = (tid>>6)&1;
    int xs = min(xseg + cix, 15);
    const float* b0p = gb + (size_t)(y0*16+xs)*2048 + k*1024 + o*64;
    const float* b1p = gb + (size_t)(y1*16+xs)*2048 + k*1024 + o*64;
    float2* d = (float2*)lds + cix*2080 + k*1040 + o*65;
    float prev = 0.f;
    if(half){
      float a = b0p[31], c = b1p[31];
      prev = fmaf(fy, c-a, a);
    }
    int j0 = half*8;
    #pragma unroll
    for(int j=0; j<8; ++j){
      int jj = j0 + j;
      float4 a = *(const float4*)(b0p + jj*4);
      float4 c = *(const float4*)(b1p + jj*4);
      float v0 = fmaf(fy, c.x-a.x, a.x);
      float v1 = fmaf(fy, c.y-a.y, a.y);
      float v2 = fmaf(fy, c.z-a.z, a.z);
      float v3 = fmaf(fy, c.w-a.w, a.w);
      if(j > 0 || half) d[4*jj-1] = make_float2(prev, v0);
      d[4*jj]   = make_float2(v0, v1);
      d[4*jj+1] = make_float2(v1, v2);
      d[4*jj+2] = make_float2(v2, v3);
      prev = v3;
    }
    if(half) d[63] = make_float2(prev, prev);
  }
  __syncthreads();

  int wv = tid>>6, lane = tid&63;
  int o = lane>>2, pl = lane&3;
  int lc = wv*4 + pl;               // 0..19 (17+ invalid)
  int wq = xseg*17 + lc;
  bool act = (lc < 17) && (wq < 256);
  int wqc = min(wq, 255);

  float fx = (float)lc * (1.f/17.f);
  float cwA = 1.f - fx, cwB = fx;
  int obase = o*65;
  const float2* l2 = (const float2*)lds;

  float acc = 0.f, bacc = 0.f;
  for(int i=0; i<CIc; i++){
    float xv = x[((size_t)(b*CIc+i)*Hc + hp)*Wc + wqc];
    float g = fminf(fmaxf(xv, 0.f), 1.f);
    float pz = g*63.f;
    int z0 = (int)pz; float fz = pz - (float)z0;
    float wz0 = cwA*(1.f-fz), wz1 = cwA*fz;
    float vz0 = cwB*(1.f-fz), vz1 = cwB*fz;
    int aA = obase + z0, aB = 2080 + obase + z0;
    float2 wA = l2[aA],        wB = l2[aB];
    float2 bA = l2[aA + 1040], bB = l2[aB + 1040];
    float wsum = fmaf(wz0, wA.x, fmaf(wz1, wA.y, fmaf(vz0, wB.x, vz1*wB.y)));
    float bsum = fmaf(wz0, bA.x, fmaf(wz1, bA.y, fmaf(vz0, bB.x, vz1*bB.y)));
    acc  = fmaf(xv, wsum, acc);
    bacc += bsum;
  }
  float vout = act ? (acc + bacc*(1.f/16.f)) : 0.f;
  if(act)
    outp[((size_t)(b*COc+o)*Hc + hp)*Wc + wq] = vout;

  float sm = vout, sq = vout*vout;
  sm += __shfl_xor(sm,1); sq += __shfl_xor(sq,1);
  sm += __shfl_xor(sm,2); sq += __shfl_xor(sq,2);
  __syncthreads();
  if(pl==0){ lds[(wv*16+o)*2] = sm; lds[(wv*16+o)*2+1] = sq; }
  __syncthreads();
  if(tid < 32){
    int oo = tid>>1, kd = tid&1;
    float S = (((lds[(0*16+oo)*2+kd] + lds[(1*16+oo)*2+kd])
             +  (lds[(2*16+oo)*2+kd] + lds[(3*16+oo)*2+kd]))
             +   lds[(4*16+oo)*2+kd]);
    int blk = (b*256 + hp)*16 + xseg;       // P=8192
    pacc[kd*131072 + oo*8192 + blk] = S;    // CP = 16*8192
  }
}

// ---- final BN + SiLU in place on d_out ----
__global__ void k_final(float* __restrict__ out, const float* __restrict__ A,
                        const float* __restrict__ B){
  int idx = blockIdx.x*256 + threadIdx.x;
  int c = (idx>>16)&15;
  float y = fmaf(out[idx], A[c], B[c]);
  out[idx] = y / (1.f + expf(-y));
}

} // namespace

extern "C" void kernel_launch(void* const* d_in, const int* in_sizes, int n_in,
                              void* d_out, int out_size, void* d_ws, size_t ws_size,
                              hipStream_t stream){
  const float* x       = (const float*)d_in[0];
  const float* conv0_w = (const float*)d_in[1];
  const float* conv0_b = (const float*)d_in[2];
  const float* prelu0  = (const float*)d_in[3];
  const float* c1w  = (const float*)d_in[4];
  const float* c1b  = (const float*)d_in[5];
  const float* bn1g = (const float*)d_in[6];
  const float* bn1b = (const float*)d_in[7];
  const float* p1   = (const float*)d_in[8];
  const float* dww  = (const float*)d_in[9];
  const float* dwb  = (const float*)d_in[10];
  const float* bn2g = (const float*)d_in[11];
  const float* bn2b = (const float*)d_in[12];
  const float* p2   = (const float*)d_in[13];
  const float* c3w  = (const float*)d_in[14];
  const float* c3b  = (const float*)d_in[15];
  const float* bn3g = (const float*)d_in[16];
  const float* bn3b = (const float*)d_in[17];
  const float* p3   = (const float*)d_in[18];
  const float* hw   = (const float*)d_in[19];
  const float* hb   = (const float*)d_in[20];
  const float* obg  = (const float*)d_in[21];
  const float* obb  = (const float*)d_in[22];
  float* out = (float*)d_out;
  float* ws  = (float*)d_ws;

  // workspace (floats)
  float* xd    = ws;                 // 131072
  float* h     = xd + 131072;        // 524288  spatial-major [b][s][64]
  float* A     = h  + 524288;        // 320
  float* B     = A  + 320;           // 320
  float* pacc  = B  + 320;           // 81920  BN1 partials
  float* paccb = pacc + 81920;       // 20480  BN2 partials
  float* paccc = paccb + 20480;      // 65536  BN3 partials
  float* t1    = paccc + 65536;      // 2621440
  float* t2    = t1 + 2621440;       // 2621440
  float* ts    = t2 + 2621440;       // 524288  spatial-major [b][s][64]
  float* gv    = t1;                 // 4194304 aliases t1+t2 (dead by head)
  float* pacc2 = ts;                 // 262144 slice partials alias ts

  k_down <<<512,  256, 0, stream>>>(x, xd);
  k_conv0<<<2048, 256, 0, stream>>>(xd, conv0_w, conv0_b, prelu0, h);

  for(int i=0; i<3; i++){
    k_c1  <<<dim3(8,64,Bn), 256, 0, stream>>>(h, c1w + i*20480, c1b + i*320, t1, pacc);
    k_dw_s<<<10240, 256, 0, stream>>>(t1, dww + i*2880, dwb + i*320,
                                      bn1g+i*320, bn1b+i*320, p1+i, pacc, t2, paccb);
    k_c3f <<<dim3(256,Bn), 256, 0, stream>>>(t2, c3w + i*20480, c3b + i*64,
                                             bn2g+i*320, bn2b+i*320, p2+i, paccb, ts, paccc);
    k_fin <<<64, 256, 0, stream>>>(paccc, 512, 1.f/8192.f, bn3g+i*64, bn3b+i*64, A, B);
    k_addres<<<2048, 256, 0, stream>>>(ts, h, p3+i, A, B);
  }

  k_head_t<<<512, 256, 0, stream>>>(h, hw, hb, gv);
  k_slice <<<dim3(16,256,Bn), 320, 0, stream>>>(x, gv, out, pacc2);
  k_fin   <<<16, 256, 0, stream>>>(pacc2, 8192, 1.f/131072.f, obg, obb, A, B);
  k_final <<<8192, 256, 0, stream>>>(out, A, B);
}

// Round 23
// 463.842 us; speedup vs baseline: 1.2670x; 1.2670x over previous
//
#include <hip/hip_runtime.h>
#include <math.h>

namespace {

constexpr int Bn=2, CIc=16, COc=16, Hc=256, Wc=256, HIDc=64, C5c=320;
constexpr int SPc = 4096;               // 64*64
constexpr float EPSc = 1e-5f;

// ---- 4x4 mean downsample: x (B,16,256,256) -> xd (B,16,64,64) ----
__global__ void k_down(const float* __restrict__ x, float* __restrict__ xd){
  int idx = blockIdx.x*blockDim.x + threadIdx.x;
  if (idx >= Bn*CIc*SPc) return;
  int q = idx & 63, p = (idx>>6)&63, c = idx>>12;
  const float* xp = x + ((size_t)c*Hc + p*4)*Wc + q*4;
  float s = 0.f;
  #pragma unroll
  for(int dy=0; dy<4; dy++)
    #pragma unroll
    for(int dx=0; dx<4; dx++) s += xp[dy*Wc+dx];
  xd[idx] = s * (1.f/16.f);
}

// ---- conv0 3x3 pad1 (16->64) + scalar PReLU ----
__global__ void k_conv0(const float* __restrict__ xd, const float* __restrict__ w,
                        const float* __restrict__ bias, const float* __restrict__ a0,
                        float* __restrict__ h){
  int idx = blockIdx.x*blockDim.x + threadIdx.x;
  if (idx >= Bn*HIDc*SPc) return;
  int q = idx&63, p=(idx>>6)&63, co=(idx>>12)&63, b=idx/(HIDc*SPc);
  float acc = bias[co];
  for(int ci=0; ci<CIc; ci++){
    const float* xp = xd + (size_t)(b*CIc+ci)*SPc;
    const float* wp = w + (co*CIc+ci)*9;
    #pragma unroll
    for(int u=0; u<3; u++){
      int pp = p+u-1; if((unsigned)pp >= 64u) continue;
      #pragma unroll
      for(int v=0; v<3; v++){
        int qq = q+v-1; if((unsigned)qq >= 64u) continue;
        acc = fmaf(xp[pp*64+qq], wp[u*3+v], acc);
      }
    }
  }
  float a = a0[0];
  h[idx] = acc >= 0.f ? acc : a*acc;
}

// ---- fused 1x1 conv 64->320 + BN1 stat partials ----
__global__ void k_c1(const float* __restrict__ h, const float* __restrict__ w,
                     const float* __restrict__ bias, float* __restrict__ t1,
                     float* __restrict__ pacc){
  __shared__ float lh[64*64];
  int og = blockIdx.x, sj = blockIdx.y, b = blockIdx.z;
  int tid = threadIdx.x;
  for(int it=0; it<4; ++it){
    int f4 = tid + it*256;               // c*16 + s4
    int c = f4>>4, s4 = f4&15;
    float4 v = *(const float4*)(h + (size_t)(b*64+c)*SPc + sj*64 + s4*4);
    *(float4*)(&lh[c*64 + s4*4]) = v;
  }
  __syncthreads();
  int osub = tid>>6, s = tid&63;
  int ob = og*40 + osub*10;
  float acc[10];
  #pragma unroll
  for(int j=0;j<10;j++) acc[j] = bias[ob+j];
  for(int c=0;c<64;c++){
    float hv = lh[c*64+s];
    #pragma unroll
    for(int j=0;j<10;j++) acc[j] = fmaf(hv, w[(ob+j)*64 + c], acc[j]);
  }
  #pragma unroll
  for(int j=0;j<10;j++){
    int o = ob+j;
    t1[(size_t)(b*320+o)*SPc + sj*64 + s] = acc[j];
    float sm = acc[j], sq = acc[j]*acc[j];
    #pragma unroll
    for(int d=1; d<64; d<<=1){ sm += __shfl_xor(sm,d); sq += __shfl_xor(sq,d); }
    if(s==0){
      pacc[o*128 + b*64 + sj]         = sm;   // P=128
      pacc[40960 + o*128 + b*64 + sj] = sq;   // CP = 320*128
    }
  }
}

// ---- finalize: partials -> fused BN scale/shift A,B ----
__global__ void k_fin(const float* __restrict__ pacc, int P, float invN,
                      const float* __restrict__ g, const float* __restrict__ bb,
                      float* __restrict__ A, float* __restrict__ B){
  __shared__ double sh[256], sh2[256];
  int c = blockIdx.x, C = gridDim.x, tid = threadIdx.x;
  double s=0.0, s2=0.0;
  for(int p=tid; p<P; p+=256){
    s  += (double)pacc[c*P+p];
    s2 += (double)pacc[C*P + c*P + p];
  }
  sh[tid]=s; sh2[tid]=s2; __syncthreads();
  for(int off=128; off>0; off>>=1){
    if(tid<off){ sh[tid]+=sh[tid+off]; sh2[tid]+=sh2[tid+off]; }
    __syncthreads();
  }
  if(tid==0){
    float m = (float)(sh[0]*(double)invN);
    float v = (float)(sh2[0]*(double)invN) - m*m;
    float r = rsqrtf(v + EPSc);
    float gc = g[c];
    A[c] = gc*r;
    B[c] = bb[c] - m*gc*r;
  }
}

// ---- depthwise 3x3; BN1 finalized in prologue; BN2 partials out ----
__global__ void k_dw_s(const float* __restrict__ t1, const float* __restrict__ w,
                       const float* __restrict__ bias, const float* __restrict__ g1,
                       const float* __restrict__ bb1, const float* __restrict__ ap,
                       const float* __restrict__ pin, float* __restrict__ t2,
                       float* __restrict__ pout){
  int tid = threadIdx.x;
  int idx = blockIdx.x*256 + tid;
  int q = idx&63, p=(idx>>6)&63, c=(idx>>12)%C5c, b=idx/(C5c*SPc);
  __shared__ float sAB[2];
  __shared__ float ws4[4];
  {
    float v = (tid<128) ? pin[c*128 + tid] : pin[40960 + c*128 + (tid-128)];
    #pragma unroll
    for(int d=1; d<64; d<<=1) v += __shfl_xor(v, d);
    int wv = tid>>6, ln = tid&63;
    if(ln==0) ws4[wv] = v;
    __syncthreads();
    if(tid==0){
      float S = ws4[0]+ws4[1], Q = ws4[2]+ws4[3];
      float m = S*(1.f/8192.f);
      float var = Q*(1.f/8192.f) - m*m;
      float r = rsqrtf(var + EPSc);
      float gc = g1[c];
      sAB[0] = gc*r; sAB[1] = bb1[c] - m*gc*r;
    }
    __syncthreads();
  }
  float a1 = sAB[0], b1 = sAB[1], al = ap[0];
  const float* ip = t1 + (size_t)(b*C5c+c)*SPc;
  const float* wp = w + c*9;
  float acc = bias[c];
  #pragma unroll
  for(int u=0; u<3; u++){
    int pp = p+u-1; if((unsigned)pp >= 64u) continue;
    #pragma unroll
    for(int v=0; v<3; v++){
      int qq = q+v-1; if((unsigned)qq >= 64u) continue;
      float y = fmaf(ip[pp*64+qq], a1, b1);
      y = y >= 0.f ? y : al*y;
      acc = fmaf(y, wp[u*3+v], acc);
    }
  }
  t2[idx] = acc;
  float sm = acc, sq = acc*acc;
  #pragma unroll
  for(int d=1; d<64; d<<=1){ sm += __shfl_xor(sm,d); sq += __shfl_xor(sq,d); }
  __shared__ float sred[8];
  int wv = tid>>6, ln = tid&63;
  if(ln==0){ sred[wv]=sm; sred[4+wv]=sq; }
  __syncthreads();
  if(tid==0){
    float S = ((sred[0]+sred[1])+(sred[2]+sred[3]));
    float Q = ((sred[4]+sred[5])+(sred[6]+sred[7]));
    int j = blockIdx.x & 15;
    pout[c*32 + b*16 + j]         = S;   // P=32
    pout[10240 + c*32 + b*16 + j] = Q;   // CP = 320*32
  }
}

// ---- full-K 1x1 conv 320->64; BN2 finalized in prologue; BN3 partials out ----
// grid (256 sjf, Bn), 256 thr = 16 og x 16 s. Block: 16 px, all 320 in-ch.
__global__ void k_c3f(const float* __restrict__ t2, const float* __restrict__ w,
                      const float* __restrict__ bias, const float* __restrict__ g2,
                      const float* __restrict__ bb2, const float* __restrict__ ap,
                      const float* __restrict__ pin, float* __restrict__ ts,
                      float* __restrict__ pout){
  __shared__ float sA[320], sB[320];
  __shared__ float li[320*16];    // 20 KB
  int sjf = blockIdx.x, b = blockIdx.y;
  int tid = threadIdx.x;
  for(int c = tid; c < 320; c += 256){
    const float4* ps = (const float4*)(pin + c*32);
    const float4* pq = (const float4*)(pin + 10240 + c*32);
    float S=0.f, Q=0.f;
    #pragma unroll
    for(int j=0;j<8;j++){ float4 a = ps[j]; S += ((a.x+a.y)+(a.z+a.w)); }
    #pragma unroll
    for(int j=0;j<8;j++){ float4 a = pq[j]; Q += ((a.x+a.y)+(a.z+a.w)); }
    float m = S*(1.f/8192.f);
    float var = Q*(1.f/8192.f) - m*m;
    float r = rsqrtf(var + EPSc);
    float gc = g2[c];
    sA[c] = gc*r; sB[c] = bb2[c] - m*gc*r;
  }
  __syncthreads();
  float al = ap[0];
  for(int t = tid; t < 1280; t += 256){
    int c = t>>2, k4 = t&3;
    float4 v = *(const float4*)(t2 + (size_t)(b*C5c+c)*SPc + sjf*16 + k4*4);
    float a1 = sA[c], b1 = sB[c];
    float4 y;
    y.x = fmaf(v.x, a1, b1); y.x = y.x>=0.f ? y.x : al*y.x;
    y.y = fmaf(v.y, a1, b1); y.y = y.y>=0.f ? y.y : al*y.y;
    y.z = fmaf(v.z, a1, b1); y.z = y.z>=0.f ? y.z : al*y.z;
    y.w = fmaf(v.w, a1, b1); y.w = y.w>=0.f ? y.w : al*y.w;
    *(float4*)(&li[c*16 + k4*4]) = y;
  }
  __syncthreads();
  int og = tid>>4, s = tid&15;
  float acc[4];
  #pragma unroll
  for(int j=0;j<4;j++) acc[j] = bias[og*4+j];
  const float* wb = w + (size_t)(og*4)*C5c;
  for(int c=0; c<320; c++){
    float hv = li[c*16 + s];
    #pragma unroll
    for(int j=0;j<4;j++)
      acc[j] = fmaf(hv, wb[j*C5c + c], acc[j]);
  }
  #pragma unroll
  for(int j=0;j<4;j++){
    int o = og*4+j;
    ts[(size_t)(b*64+o)*SPc + sjf*16 + s] = acc[j];
    float sm = acc[j], sq = acc[j]*acc[j];
    #pragma unroll
    for(int d=1; d<16; d<<=1){ sm += __shfl_xor(sm,d); sq += __shfl_xor(sq,d); }
    if(s==0){
      pout[o*512 + b*256 + sjf]         = sm;  // P=512
      pout[32768 + o*512 + b*256 + sjf] = sq;  // CP = 64*512
    }
  }
}

// ---- BN3 (A,B precomputed by k_fin) + PReLU3 + residual add into h ----
__global__ void k_addres(const float* __restrict__ ts, float* __restrict__ h,
                         const float* __restrict__ ap, const float* __restrict__ A,
                         const float* __restrict__ B){
  int idx = blockIdx.x*256 + threadIdx.x;
  int c = (idx>>12)&63;
  float y = fmaf(ts[idx], A[c], B[c]);
  float al = ap[0];
  y = y >= 0.f ? y : al*y;
  h[idx] += y;
}

// ---- head 1x1 conv (64->512) writing z-innermost gvol, chunk=[k2][o16][z64] ----
__global__ void k_head_t(const float* __restrict__ h, const float* __restrict__ w,
                         const float* __restrict__ bias, float* __restrict__ gv){
  __shared__ float sb0[64*65], sb1[64*65];
  int bid = blockIdx.x;            // (b*16 + o)*16 + ci
  int ci = bid & 15, o = (bid>>4) & 15, b = bid >> 8;
  int c0 = (o*16 + ci)*2, c1 = c0 + 1;
  const float* hp0 = h + (size_t)b*HIDc*SPc;
  const float* w0 = w + (size_t)c0*HIDc;
  const float* w1 = w + (size_t)c1*HIDc;
  float b0 = bias[c0], b1 = bias[c1];
  int tid = threadIdx.x;
  for(int j=0; j<16; j++){
    int s = tid + j*256;           // s = p*64 + q
    float a0 = b0, a1 = b1;
    #pragma unroll 8
    for(int kc=0; kc<HIDc; kc++){
      float hv = hp0[kc*SPc + s];
      a0 = fmaf(hv, w0[kc], a0);
      a1 = fmaf(hv, w1[kc], a1);
    }
    int pad = s + (s>>6);
    sb0[pad] = a0; sb1[pad] = a1;
  }
  __syncthreads();
  float* gb = gv + (size_t)b*(64*16*2048);
  for(int j=0; j<16; j++){
    int t = tid + j*256;
    int q = t>>6, p = t&63;
    size_t base = ((size_t)(q*16 + ci))*2048 + (size_t)o*64 + p;
    gb[base]        = sb0[p*65 + q];   // k=0 weight plane
    gb[base + 1024] = sb1[p*65 + q];   // k=1 bias plane
  }
}

// ---- slice v4: 17-col segments (x0 block-uniform), 1 row/block, 320 thr ----
__global__ void k_slice(const float* __restrict__ x, const float* __restrict__ gv,
                        float* __restrict__ outp, float* __restrict__ pacc){
  __shared__ float lds[8320];     // 4160 float2
  int xseg = blockIdx.x, hp = blockIdx.y, b = blockIdx.z;
  int tid = threadIdx.x;
  const float* gb = gv + (size_t)b*(64*16*2048);
  int y0 = (hp*63)/255;
  int y1 = min(y0+1, 63);
  float fy = hp*(63.f/255.f) - (float)y0;

  if(tid < 128){
    int half = tid & 1, o = (tid>>1)&15, k = (tid>>5)&1, cix = (tid>>6)&1;
    int xs = min(xseg + cix, 15);
    const float* b0p = gb + (size_t)(y0*16+xs)*2048 + k*1024 + o*64;
    const float* b1p = gb + (size_t)(y1*16+xs)*2048 + k*1024 + o*64;
    float2* d = (float2*)lds + cix*2080 + k*1040 + o*65;
    float prev = 0.f;
    if(half){
      float a = b0p[31], c = b1p[31];
      prev = fmaf(fy, c-a, a);
    }
    int j0 = half*8;
    #pragma unroll
    for(int j=0; j<8; ++j){
      int jj = j0 + j;
      float4 a = *(const float4*)(b0p + jj*4);
      float4 c = *(const float4*)(b1p + jj*4);
      float v0 = fmaf(fy, c.x-a.x, a.x);
      float v1 = fmaf(fy, c.y-a.y, a.y);
      float v2 = fmaf(fy, c.z-a.z, a.z);
      float v3 = fmaf(fy, c.w-a.w, a.w);
      if(j > 0 || half) d[4*jj-1] = make_float2(prev, v0);
      d[4*jj]   = make_float2(v0, v1);
      d[4*jj+1] = make_float2(v1, v2);
      d[4*jj+2] = make_float2(v2, v3);
      prev = v3;
    }
    if(half) d[63] = make_float2(prev, prev);
  }
  __syncthreads();

  int wv = tid>>6, lane = tid&63;
  int o = lane>>2, pl = lane&3;
  int lc = wv*4 + pl;               // 0..19 (17+ invalid)
  int wq = xseg*17 + lc;
  bool act = (lc < 17) && (wq < 256);
  int wqc = min(wq, 255);

  float fx = (float)lc * (1.f/17.f);
  float cwA = 1.f - fx, cwB = fx;
  int obase = o*65;
  const float2* l2 = (const float2*)lds;

  float acc = 0.f, bacc = 0.f;
  for(int i=0; i<CIc; i++){
    float xv = x[((size_t)(b*CIc+i)*Hc + hp)*Wc + wqc];
    float g = fminf(fmaxf(xv, 0.f), 1.f);
    float pz = g*63.f;
    int z0 = (int)pz; float fz = pz - (float)z0;
    float wz0 = cwA*(1.f-fz), wz1 = cwA*fz;
    float vz0 = cwB*(1.f-fz), vz1 = cwB*fz;
    int aA = obase + z0, aB = 2080 + obase + z0;
    float2 wA = l2[aA],        wB = l2[aB];
    float2 bA = l2[aA + 1040], bB = l2[aB + 1040];
    float wsum = fmaf(wz0, wA.x, fmaf(wz1, wA.y, fmaf(vz0, wB.x, vz1*wB.y)));
    float bsum = fmaf(wz0, bA.x, fmaf(wz1, bA.y, fmaf(vz0, bB.x, vz1*bB.y)));
    acc  = fmaf(xv, wsum, acc);
    bacc += bsum;
  }
  float vout = act ? (acc + bacc*(1.f/16.f)) : 0.f;
  if(act)
    outp[((size_t)(b*COc+o)*Hc + hp)*Wc + wq] = vout;

  float sm = vout, sq = vout*vout;
  sm += __shfl_xor(sm,1); sq += __shfl_xor(sq,1);
  sm += __shfl_xor(sm,2); sq += __shfl_xor(sq,2);
  __syncthreads();
  if(pl==0){ lds[(wv*16+o)*2] = sm; lds[(wv*16+o)*2+1] = sq; }
  __syncthreads();
  if(tid < 32){
    int oo = tid>>1, kd = tid&1;
    float S = (((lds[(0*16+oo)*2+kd] + lds[(1*16+oo)*2+kd])
             +  (lds[(2*16+oo)*2+kd] + lds[(3*16+oo)*2+kd]))
             +   lds[(4*16+oo)*2+kd]);
    int blk = (b*256 + hp)*16 + xseg;       // P=8192
    pacc[kd*131072 + oo*8192 + blk] = S;    // CP = 16*8192
  }
}

// ---- final BN + SiLU in place on d_out ----
__global__ void k_final(float* __restrict__ out, const float* __restrict__ A,
                        const float* __restrict__ B){
  int idx = blockIdx.x*256 + threadIdx.x;
  int c = (idx>>16)&15;
  float y = fmaf(out[idx], A[c], B[c]);
  out[idx] = y / (1.f + expf(-y));
}

} // namespace

extern "C" void kernel_launch(void* const* d_in, const int* in_sizes, int n_in,
                              void* d_out, int out_size, void* d_ws, size_t ws_size,
                              hipStream_t stream){
  const float* x       = (const float*)d_in[0];
  const float* conv0_w = (const float*)d_in[1];
  const float* conv0_b = (const float*)d_in[2];
  const float* prelu0  = (const float*)d_in[3];
  const float* c1w  = (const float*)d_in[4];
  const float* c1b  = (const float*)d_in[5];
  const float* bn1g = (const float*)d_in[6];
  const float* bn1b = (const float*)d_in[7];
  const float* p1   = (const float*)d_in[8];
  const float* dww  = (const float*)d_in[9];
  const float* dwb  = (const float*)d_in[10];
  const float* bn2g = (const float*)d_in[11];
  const float* bn2b = (const float*)d_in[12];
  const float* p2   = (const float*)d_in[13];
  const float* c3w  = (const float*)d_in[14];
  const float* c3b  = (const float*)d_in[15];
  const float* bn3g = (const float*)d_in[16];
  const float* bn3b = (const float*)d_in[17];
  const float* p3   = (const float*)d_in[18];
  const float* hw   = (const float*)d_in[19];
  const float* hb   = (const float*)d_in[20];
  const float* obg  = (const float*)d_in[21];
  const float* obb  = (const float*)d_in[22];
  float* out = (float*)d_out;
  float* ws  = (float*)d_ws;

  // workspace (floats)
  float* xd    = ws;                 // 131072
  float* h     = xd + 131072;        // 524288
  float* A     = h  + 524288;        // 320
  float* B     = A  + 320;           // 320
  float* pacc  = B  + 320;           // 81920  BN1 partials
  float* paccb = pacc + 81920;       // 20480  BN2 partials
  float* paccc = paccb + 20480;      // 65536  BN3 partials
  float* t1    = paccc + 65536;      // 2621440
  float* t2    = t1 + 2621440;       // 2621440
  float* ts    = t2 + 2621440;       // 524288
  float* gv    = t1;                 // 4194304 aliases t1+t2 (dead by head)
  float* pacc2 = ts;                 // 262144 slice partials alias ts

  k_down <<<512,  256, 0, stream>>>(x, xd);
  k_conv0<<<2048, 256, 0, stream>>>(xd, conv0_w, conv0_b, prelu0, h);

  for(int i=0; i<3; i++){
    k_c1  <<<dim3(8,64,Bn), 256, 0, stream>>>(h, c1w + i*20480, c1b + i*320, t1, pacc);
    k_dw_s<<<10240, 256, 0, stream>>>(t1, dww + i*2880, dwb + i*320,
                                      bn1g+i*320, bn1b+i*320, p1+i, pacc, t2, paccb);
    k_c3f <<<dim3(256,Bn), 256, 0, stream>>>(t2, c3w + i*20480, c3b + i*64,
                                             bn2g+i*320, bn2b+i*320, p2+i, paccb, ts, paccc);
    k_fin <<<64, 256, 0, stream>>>(paccc, 512, 1.f/8192.f, bn3g+i*64, bn3b+i*64, A, B);
    k_addres<<<2048, 256, 0, stream>>>(ts, h, p3+i, A, B);
  }

  k_head_t<<<512, 256, 0, stream>>>(h, hw, hb, gv);
  k_slice <<<dim3(16,256,Bn), 320, 0, stream>>>(x, gv, out, pacc2);
  k_fin   <<<16, 256, 0, stream>>>(pacc2, 8192, 1.f/131072.f, obg, obb, A, B);
  k_final <<<8192, 256, 0, stream>>>(out, A, B);
}

// Round 24
// 458.911 us; speedup vs baseline: 1.2807x; 1.0107x over previous
//
#include <hip/hip_runtime.h>
#include <math.h>

namespace {

constexpr int Bn=2, CIc=16, COc=16, Hc=256, Wc=256, HIDc=64, C5c=320;
constexpr int SPc = 4096;               // 64*64
constexpr float EPSc = 1e-5f;

// ---- 4x4 mean downsample: x (B,16,256,256) -> xd (B,16,64,64) ----
__global__ void k_down(const float* __restrict__ x, float* __restrict__ xd){
  int idx = blockIdx.x*blockDim.x + threadIdx.x;
  if (idx >= Bn*CIc*SPc) return;
  int q = idx & 63, p = (idx>>6)&63, c = idx>>12;
  const float* xp = x + ((size_t)c*Hc + p*4)*Wc + q*4;
  float s = 0.f;
  #pragma unroll
  for(int dy=0; dy<4; dy++)
    #pragma unroll
    for(int dx=0; dx<4; dx++) s += xp[dy*Wc+dx];
  xd[idx] = s * (1.f/16.f);
}

// ---- conv0 3x3 pad1 (16->64) + scalar PReLU ----
__global__ void k_conv0(const float* __restrict__ xd, const float* __restrict__ w,
                        const float* __restrict__ bias, const float* __restrict__ a0,
                        float* __restrict__ h){
  int idx = blockIdx.x*blockDim.x + threadIdx.x;
  if (idx >= Bn*HIDc*SPc) return;
  int q = idx&63, p=(idx>>6)&63, co=(idx>>12)&63, b=idx/(HIDc*SPc);
  float acc = bias[co];
  for(int ci=0; ci<CIc; ci++){
    const float* xp = xd + (size_t)(b*CIc+ci)*SPc;
    const float* wp = w + (co*CIc+ci)*9;
    #pragma unroll
    for(int u=0; u<3; u++){
      int pp = p+u-1; if((unsigned)pp >= 64u) continue;
      #pragma unroll
      for(int v=0; v<3; v++){
        int qq = q+v-1; if((unsigned)qq >= 64u) continue;
        acc = fmaf(xp[pp*64+qq], wp[u*3+v], acc);
      }
    }
  }
  float a = a0[0];
  h[idx] = acc >= 0.f ? acc : a*acc;
}

// ---- fused 1x1 conv 64->320 + BN1 stat partials ----
__global__ void k_c1(const float* __restrict__ h, const float* __restrict__ w,
                     const float* __restrict__ bias, float* __restrict__ t1,
                     float* __restrict__ pacc){
  __shared__ float lh[64*64];
  int og = blockIdx.x, sj = blockIdx.y, b = blockIdx.z;
  int tid = threadIdx.x;
  for(int it=0; it<4; ++it){
    int f4 = tid + it*256;               // c*16 + s4
    int c = f4>>4, s4 = f4&15;
    float4 v = *(const float4*)(h + (size_t)(b*64+c)*SPc + sj*64 + s4*4);
    *(float4*)(&lh[c*64 + s4*4]) = v;
  }
  __syncthreads();
  int osub = tid>>6, s = tid&63;
  int ob = og*40 + osub*10;
  float acc[10];
  #pragma unroll
  for(int j=0;j<10;j++) acc[j] = bias[ob+j];
  for(int c=0;c<64;c++){
    float hv = lh[c*64+s];
    #pragma unroll
    for(int j=0;j<10;j++) acc[j] = fmaf(hv, w[(ob+j)*64 + c], acc[j]);
  }
  #pragma unroll
  for(int j=0;j<10;j++){
    int o = ob+j;
    t1[(size_t)(b*320+o)*SPc + sj*64 + s] = acc[j];
    float sm = acc[j], sq = acc[j]*acc[j];
    #pragma unroll
    for(int d=1; d<64; d<<=1){ sm += __shfl_xor(sm,d); sq += __shfl_xor(sq,d); }
    if(s==0){
      pacc[o*128 + b*64 + sj]         = sm;   // P=128
      pacc[40960 + o*128 + b*64 + sj] = sq;   // CP = 320*128
    }
  }
}

// ---- finalize (out-BN only): partials -> A,B ----
__global__ void k_fin(const float* __restrict__ pacc, int P, float invN,
                      const float* __restrict__ g, const float* __restrict__ bb,
                      float* __restrict__ A, float* __restrict__ B){
  __shared__ double sh[256], sh2[256];
  int c = blockIdx.x, C = gridDim.x, tid = threadIdx.x;
  double s=0.0, s2=0.0;
  for(int p=tid; p<P; p+=256){
    s  += (double)pacc[c*P+p];
    s2 += (double)pacc[C*P + c*P + p];
  }
  sh[tid]=s; sh2[tid]=s2; __syncthreads();
  for(int off=128; off>0; off>>=1){
    if(tid<off){ sh[tid]+=sh[tid+off]; sh2[tid]+=sh2[tid+off]; }
    __syncthreads();
  }
  if(tid==0){
    float m = (float)(sh[0]*(double)invN);
    float v = (float)(sh2[0]*(double)invN) - m*m;
    float r = rsqrtf(v + EPSc);
    float gc = g[c];
    A[c] = gc*r;
    B[c] = bb[c] - m*gc*r;
  }
}

// ---- depthwise 3x3; BN1 finalized in prologue; BN2 partials out ----
__global__ void k_dw_s(const float* __restrict__ t1, const float* __restrict__ w,
                       const float* __restrict__ bias, const float* __restrict__ g1,
                       const float* __restrict__ bb1, const float* __restrict__ ap,
                       const float* __restrict__ pin, float* __restrict__ t2,
                       float* __restrict__ pout){
  int tid = threadIdx.x;
  int idx = blockIdx.x*256 + tid;
  int q = idx&63, p=(idx>>6)&63, c=(idx>>12)%C5c, b=idx/(C5c*SPc);
  __shared__ float sAB[2];
  __shared__ float ws4[4];
  {
    float v = (tid<128) ? pin[c*128 + tid] : pin[40960 + c*128 + (tid-128)];
    #pragma unroll
    for(int d=1; d<64; d<<=1) v += __shfl_xor(v, d);
    int wv = tid>>6, ln = tid&63;
    if(ln==0) ws4[wv] = v;
    __syncthreads();
    if(tid==0){
      float S = ws4[0]+ws4[1], Q = ws4[2]+ws4[3];
      float m = S*(1.f/8192.f);
      float var = Q*(1.f/8192.f) - m*m;
      float r = rsqrtf(var + EPSc);
      float gc = g1[c];
      sAB[0] = gc*r; sAB[1] = bb1[c] - m*gc*r;
    }
    __syncthreads();
  }
  float a1 = sAB[0], b1 = sAB[1], al = ap[0];
  const float* ip = t1 + (size_t)(b*C5c+c)*SPc;
  const float* wp = w + c*9;
  float acc = bias[c];
  #pragma unroll
  for(int u=0; u<3; u++){
    int pp = p+u-1; if((unsigned)pp >= 64u) continue;
    #pragma unroll
    for(int v=0; v<3; v++){
      int qq = q+v-1; if((unsigned)qq >= 64u) continue;
      float y = fmaf(ip[pp*64+qq], a1, b1);
      y = y >= 0.f ? y : al*y;
      acc = fmaf(y, wp[u*3+v], acc);
    }
  }
  t2[idx] = acc;
  float sm = acc, sq = acc*acc;
  #pragma unroll
  for(int d=1; d<64; d<<=1){ sm += __shfl_xor(sm,d); sq += __shfl_xor(sq,d); }
  __shared__ float sred[8];
  int wv = tid>>6, ln = tid&63;
  if(ln==0){ sred[wv]=sm; sred[4+wv]=sq; }
  __syncthreads();
  if(tid==0){
    float S = ((sred[0]+sred[1])+(sred[2]+sred[3]));
    float Q = ((sred[4]+sred[5])+(sred[6]+sred[7]));
    int j = blockIdx.x & 15;
    pout[c*32 + b*16 + j]         = S;   // P=32
    pout[10240 + c*32 + b*16 + j] = Q;   // CP = 320*32
  }
}

// ---- full-K 1x1 conv 320->64; BN2 finalized in prologue; BN3 partials out ----
// grid (256 sjf, Bn), 256 thr = 16 og x 16 s. Block: 16 px, all 320 in-ch.
__global__ void k_c3f(const float* __restrict__ t2, const float* __restrict__ w,
                      const float* __restrict__ bias, const float* __restrict__ g2,
                      const float* __restrict__ bb2, const float* __restrict__ ap,
                      const float* __restrict__ pin, float* __restrict__ ts,
                      float* __restrict__ pout){
  __shared__ float sA[320], sB[320];
  __shared__ float li[320*16];    // 20 KB
  int sjf = blockIdx.x, b = blockIdx.y;
  int tid = threadIdx.x;
  for(int c = tid; c < 320; c += 256){
    const float4* ps = (const float4*)(pin + c*32);
    const float4* pq = (const float4*)(pin + 10240 + c*32);
    float S=0.f, Q=0.f;
    #pragma unroll
    for(int j=0;j<8;j++){ float4 a = ps[j]; S += ((a.x+a.y)+(a.z+a.w)); }
    #pragma unroll
    for(int j=0;j<8;j++){ float4 a = pq[j]; Q += ((a.x+a.y)+(a.z+a.w)); }
    float m = S*(1.f/8192.f);
    float var = Q*(1.f/8192.f) - m*m;
    float r = rsqrtf(var + EPSc);
    float gc = g2[c];
    sA[c] = gc*r; sB[c] = bb2[c] - m*gc*r;
  }
  __syncthreads();
  float al = ap[0];
  for(int t = tid; t < 1280; t += 256){
    int c = t>>2, k4 = t&3;
    float4 v = *(const float4*)(t2 + (size_t)(b*C5c+c)*SPc + sjf*16 + k4*4);
    float a1 = sA[c], b1 = sB[c];
    float4 y;
    y.x = fmaf(v.x, a1, b1); y.x = y.x>=0.f ? y.x : al*y.x;
    y.y = fmaf(v.y, a1, b1); y.y = y.y>=0.f ? y.y : al*y.y;
    y.z = fmaf(v.z, a1, b1); y.z = y.z>=0.f ? y.z : al*y.z;
    y.w = fmaf(v.w, a1, b1); y.w = y.w>=0.f ? y.w : al*y.w;
    *(float4*)(&li[c*16 + k4*4]) = y;
  }
  __syncthreads();
  int og = tid>>4, s = tid&15;
  float acc[4];
  #pragma unroll
  for(int j=0;j<4;j++) acc[j] = bias[og*4+j];
  const float* wb = w + (size_t)(og*4)*C5c;
  for(int c=0; c<320; c++){
    float hv = li[c*16 + s];
    #pragma unroll
    for(int j=0;j<4;j++)
      acc[j] = fmaf(hv, wb[j*C5c + c], acc[j]);
  }
  #pragma unroll
  for(int j=0;j<4;j++){
    int o = og*4+j;
    ts[(size_t)(b*64+o)*SPc + sjf*16 + s] = acc[j];
    float sm = acc[j], sq = acc[j]*acc[j];
    #pragma unroll
    for(int d=1; d<16; d<<=1){ sm += __shfl_xor(sm,d); sq += __shfl_xor(sq,d); }
    if(s==0){
      pout[o*512 + b*256 + sjf]         = sm;  // P=512
      pout[32768 + o*512 + b*256 + sjf] = sq;  // CP = 64*512
    }
  }
}

// ---- BN3 (finalized in prologue, P=512) + PReLU3 + residual add into h ----
__global__ void k_addres(const float* __restrict__ ts, float* __restrict__ h,
                         const float* __restrict__ g3, const float* __restrict__ bb3,
                         const float* __restrict__ ap, const float* __restrict__ pin){
  int tid = threadIdx.x;
  int idx = blockIdx.x*256 + tid;
  int c = (idx>>12)&63;              // constant per block
  __shared__ float sAB[2];
  __shared__ float w8[8];
  {
    float S = pin[c*512 + tid] + pin[c*512 + 256 + tid];
    float Q = pin[32768 + c*512 + tid] + pin[32768 + c*512 + 256 + tid];
    #pragma unroll
    for(int d=1; d<64; d<<=1){ S += __shfl_xor(S,d); Q += __shfl_xor(Q,d); }
    int wv = tid>>6, ln = tid&63;
    if(ln==0){ w8[wv] = S; w8[4+wv] = Q; }
    __syncthreads();
    if(tid==0){
      float Sa = (w8[0]+w8[1])+(w8[2]+w8[3]);
      float Qa = (w8[4]+w8[5])+(w8[6]+w8[7]);
      float m = Sa*(1.f/8192.f);
      float var = Qa*(1.f/8192.f) - m*m;
      float r = rsqrtf(var + EPSc);
      float gc = g3[c];
      sAB[0] = gc*r; sAB[1] = bb3[c] - m*gc*r;
    }
    __syncthreads();
  }
  float y = fmaf(ts[idx], sAB[0], sAB[1]);
  float al = ap[0];
  y = y >= 0.f ? y : al*y;
  h[idx] += y;
}

// ---- head 1x1 conv (64->512) writing z-innermost gvol, chunk=[k2][o16][z64] ----
__global__ void k_head_t(const float* __restrict__ h, const float* __restrict__ w,
                         const float* __restrict__ bias, float* __restrict__ gv){
  __shared__ float sb0[64*65], sb1[64*65];
  int bid = blockIdx.x;            // (b*16 + o)*16 + ci
  int ci = bid & 15, o = (bid>>4) & 15, b = bid >> 8;
  int c0 = (o*16 + ci)*2, c1 = c0 + 1;
  const float* hp0 = h + (size_t)b*HIDc*SPc;
  const float* w0 = w + (size_t)c0*HIDc;
  const float* w1 = w + (size_t)c1*HIDc;
  float b0 = bias[c0], b1 = bias[c1];
  int tid = threadIdx.x;
  for(int j=0; j<16; j++){
    int s = tid + j*256;           // s = p*64 + q
    float a0 = b0, a1 = b1;
    #pragma unroll 8
    for(int kc=0; kc<HIDc; kc++){
      float hv = hp0[kc*SPc + s];
      a0 = fmaf(hv, w0[kc], a0);
      a1 = fmaf(hv, w1[kc], a1);
    }
    int pad = s + (s>>6);
    sb0[pad] = a0; sb1[pad] = a1;
  }
  __syncthreads();
  float* gb = gv + (size_t)b*(64*16*2048);
  for(int j=0; j<16; j++){
    int t = tid + j*256;
    int q = t>>6, p = t&63;
    size_t base = ((size_t)(q*16 + ci))*2048 + (size_t)o*64 + p;
    gb[base]        = sb0[p*65 + q];   // k=0 weight plane
    gb[base + 1024] = sb1[p*65 + q];   // k=1 bias plane
  }
}

// ---- slice v5: 17-col segments, lane-transposed (16 lanes = 16 o, 1 px) ----
// grid (16 xseg, 256 row, Bn), 320 thr; conflict-free LDS reads.
__global__ void k_slice(const float* __restrict__ x, const float* __restrict__ gv,
                        float* __restrict__ outp, float* __restrict__ pacc){
  __shared__ float lds[8320];     // 4160 float2
  int xseg = blockIdx.x, hp = blockIdx.y, b = blockIdx.z;
  int tid = threadIdx.x;
  const float* gb = gv + (size_t)b*(64*16*2048);
  int y0 = (hp*63)/255;
  int y1 = min(y0+1, 63);
  float fy = hp*(63.f/255.f) - (float)y0;

  // stage + y-blend: 128 threads, each owns half a (chunk,k,o) z-line
  if(tid < 128){
    int half = tid & 1, o = (tid>>1)&15, k = (tid>>5)&1, cix = (tid>>6)&1;
    int xs = min(xseg + cix, 15);
    const float* b0p = gb + (size_t)(y0*16+xs)*2048 + k*1024 + o*64;
    const float* b1p = gb + (size_t)(y1*16+xs)*2048 + k*1024 + o*64;
    float2* d = (float2*)lds + cix*2080 + k*1040 + o*65;
    float prev = 0.f;
    if(half){
      float a = b0p[31], c = b1p[31];
      prev = fmaf(fy, c-a, a);
    }
    int j0 = half*8;
    #pragma unroll
    for(int j=0; j<8; ++j){
      int jj = j0 + j;
      float4 a = *(const float4*)(b0p + jj*4);
      float4 c = *(const float4*)(b1p + jj*4);
      float v0 = fmaf(fy, c.x-a.x, a.x);
      float v1 = fmaf(fy, c.y-a.y, a.y);
      float v2 = fmaf(fy, c.z-a.z, a.z);
      float v3 = fmaf(fy, c.w-a.w, a.w);
      if(j > 0 || half) d[4*jj-1] = make_float2(prev, v0);
      d[4*jj]   = make_float2(v0, v1);
      d[4*jj+1] = make_float2(v1, v2);
      d[4*jj+2] = make_float2(v2, v3);
      prev = v3;
    }
    if(half) d[63] = make_float2(prev, prev);
  }
  __syncthreads();

  int wv = tid>>6, lane = tid&63;
  int o = lane & 15, pl = lane >> 4;  // 16 lanes = 16 o of ONE pixel
  int lc = wv*4 + pl;                 // 0..19 (17+ invalid)
  int wq = xseg*17 + lc;
  bool act = (lc < 17) && (wq < 256);
  int wqc = min(wq, 255);

  float fx = (float)lc * (1.f/17.f);
  float cwA = 1.f - fx, cwB = fx;
  int obase = o*65;
  const float2* l2 = (const float2*)lds;

  float acc = 0.f, bacc = 0.f;
  for(int i=0; i<CIc; i++){
    float xv = x[((size_t)(b*CIc+i)*Hc + hp)*Wc + wqc];
    float g = fminf(fmaxf(xv, 0.f), 1.f);
    float pz = g*63.f;
    int z0 = (int)pz; float fz = pz - (float)z0;
    float wz0 = cwA*(1.f-fz), wz1 = cwA*fz;
    float vz0 = cwB*(1.f-fz), vz1 = cwB*fz;
    int aA = obase + z0, aB = 2080 + obase + z0;
    float2 wA = l2[aA],        wB = l2[aB];
    float2 bA = l2[aA + 1040], bB = l2[aB + 1040];
    float wsum = fmaf(wz0, wA.x, fmaf(wz1, wA.y, fmaf(vz0, wB.x, vz1*wB.y)));
    float bsum = fmaf(wz0, bA.x, fmaf(wz1, bA.y, fmaf(vz0, bB.x, vz1*bB.y)));
    acc  = fmaf(xv, wsum, acc);
    bacc += bsum;
  }
  float vout = act ? (acc + bacc*(1.f/16.f)) : 0.f;
  if(act)
    outp[((size_t)(b*COc+o)*Hc + hp)*Wc + wq] = vout;

  // deterministic stats: sum over 4 pixel-groups (lanes o-aligned), then 5 waves
  float sm = vout, sq = vout*vout;
  sm += __shfl_xor(sm,16); sq += __shfl_xor(sq,16);
  sm += __shfl_xor(sm,32); sq += __shfl_xor(sq,32);
  __syncthreads();
  if(lane < 16){ lds[(wv*16+o)*2] = sm; lds[(wv*16+o)*2+1] = sq; }
  __syncthreads();
  if(tid < 32){
    int oo = tid>>1, kd = tid&1;
    float S = (((lds[(0*16+oo)*2+kd] + lds[(1*16+oo)*2+kd])
             +  (lds[(2*16+oo)*2+kd] + lds[(3*16+oo)*2+kd]))
             +   lds[(4*16+oo)*2+kd]);
    int blk = (b*256 + hp)*16 + xseg;       // P=8192
    pacc[kd*131072 + oo*8192 + blk] = S;    // CP = 16*8192
  }
}

// ---- final BN + SiLU in place on d_out ----
__global__ void k_final(float* __restrict__ out, const float* __restrict__ A,
                        const float* __restrict__ B){
  int idx = blockIdx.x*256 + threadIdx.x;
  int c = (idx>>16)&15;
  float y = fmaf(out[idx], A[c], B[c]);
  out[idx] = y / (1.f + expf(-y));
}

} // namespace

extern "C" void kernel_launch(void* const* d_in, const int* in_sizes, int n_in,
                              void* d_out, int out_size, void* d_ws, size_t ws_size,
                              hipStream_t stream){
  const float* x       = (const float*)d_in[0];
  const float* conv0_w = (const float*)d_in[1];
  const float* conv0_b = (const float*)d_in[2];
  const float* prelu0  = (const float*)d_in[3];
  const float* c1w  = (const float*)d_in[4];
  const float* c1b  = (const float*)d_in[5];
  const float* bn1g = (const float*)d_in[6];
  const float* bn1b = (const float*)d_in[7];
  const float* p1   = (const float*)d_in[8];
  const float* dww  = (const float*)d_in[9];
  const float* dwb  = (const float*)d_in[10];
  const float* bn2g = (const float*)d_in[11];
  const float* bn2b = (const float*)d_in[12];
  const float* p2   = (const float*)d_in[13];
  const float* c3w  = (const float*)d_in[14];
  const float* c3b  = (const float*)d_in[15];
  const float* bn3g = (const float*)d_in[16];
  const float* bn3b = (const float*)d_in[17];
  const float* p3   = (const float*)d_in[18];
  const float* hw   = (const float*)d_in[19];
  const float* hb   = (const float*)d_in[20];
  const float* obg  = (const float*)d_in[21];
  const float* obb  = (const float*)d_in[22];
  float* out = (float*)d_out;
  float* ws  = (float*)d_ws;

  // workspace (floats)
  float* xd    = ws;                 // 131072
  float* h     = xd + 131072;        // 524288
  float* A     = h  + 524288;        // 320
  float* B     = A  + 320;           // 320
  float* pacc  = B  + 320;           // 81920  BN1 partials
  float* paccb = pacc + 81920;       // 20480  BN2 partials
  float* paccc = paccb + 20480;      // 65536  BN3 partials
  float* t1    = paccc + 65536;      // 2621440
  float* t2    = t1 + 2621440;       // 2621440
  float* ts    = t2 + 2621440;       // 524288
  float* gv    = t1;                 // 4194304 aliases t1+t2 (dead by head)
  float* pacc2 = ts;                 // 262144 slice partials alias ts

  k_down <<<512,  256, 0, stream>>>(x, xd);
  k_conv0<<<2048, 256, 0, stream>>>(xd, conv0_w, conv0_b, prelu0, h);

  for(int i=0; i<3; i++){
    k_c1  <<<dim3(8,64,Bn), 256, 0, stream>>>(h, c1w + i*20480, c1b + i*320, t1, pacc);
    k_dw_s<<<10240, 256, 0, stream>>>(t1, dww + i*2880, dwb + i*320,
                                      bn1g+i*320, bn1b+i*320, p1+i, pacc, t2, paccb);
    k_c3f <<<dim3(256,Bn), 256, 0, stream>>>(t2, c3w + i*20480, c3b + i*64,
                                             bn2g+i*320, bn2b+i*320, p2+i, paccb, ts, paccc);
    k_addres<<<2048, 256, 0, stream>>>(ts, h, bn3g+i*64, bn3b+i*64, p3+i, paccc);
  }

  k_head_t<<<512, 256, 0, stream>>>(h, hw, hb, gv);
  k_slice <<<dim3(16,256,Bn), 320, 0, stream>>>(x, gv, out, pacc2);
  k_fin   <<<16, 256, 0, stream>>>(pacc2, 8192, 1.f/131072.f, obg, obb, A, B);
  k_final <<<8192, 256, 0, stream>>>(out, A, B);
}

// Round 25
// 447.907 us; speedup vs baseline: 1.3121x; 1.0246x over previous
//
#include <hip/hip_runtime.h>
#include <math.h>

namespace {

constexpr int Bn=2, CIc=16, COc=16, Hc=256, Wc=256, HIDc=64, C5c=320;
constexpr int SPc = 4096;               // 64*64
constexpr float EPSc = 1e-5f;

// ---- 4x4 mean downsample: x (B,16,256,256) -> xd (B,16,64,64) ----
__global__ void k_down(const float* __restrict__ x, float* __restrict__ xd){
  int idx = blockIdx.x*blockDim.x + threadIdx.x;
  if (idx >= Bn*CIc*SPc) return;
  int q = idx & 63, p = (idx>>6)&63, c = idx>>12;
  const float* xp = x + ((size_t)c*Hc + p*4)*Wc + q*4;
  float s = 0.f;
  #pragma unroll
  for(int dy=0; dy<4; dy++)
    #pragma unroll
    for(int dx=0; dx<4; dx++) s += xp[dy*Wc+dx];
  xd[idx] = s * (1.f/16.f);
}

// ---- conv0 3x3 pad1 (16->64) + scalar PReLU ----
__global__ void k_conv0(const float* __restrict__ xd, const float* __restrict__ w,
                        const float* __restrict__ bias, const float* __restrict__ a0,
                        float* __restrict__ h){
  int idx = blockIdx.x*blockDim.x + threadIdx.x;
  if (idx >= Bn*HIDc*SPc) return;
  int q = idx&63, p=(idx>>6)&63, co=(idx>>12)&63, b=idx/(HIDc*SPc);
  float acc = bias[co];
  for(int ci=0; ci<CIc; ci++){
    const float* xp = xd + (size_t)(b*CIc+ci)*SPc;
    const float* wp = w + (co*CIc+ci)*9;
    #pragma unroll
    for(int u=0; u<3; u++){
      int pp = p+u-1; if((unsigned)pp >= 64u) continue;
      #pragma unroll
      for(int v=0; v<3; v++){
        int qq = q+v-1; if((unsigned)qq >= 64u) continue;
        acc = fmaf(xp[pp*64+qq], wp[u*3+v], acc);
      }
    }
  }
  float a = a0[0];
  h[idx] = acc >= 0.f ? acc : a*acc;
}

// ---- fused 1x1 conv 64->320 + BN1 stat partials ----
__global__ void k_c1(const float* __restrict__ h, const float* __restrict__ w,
                     const float* __restrict__ bias, float* __restrict__ t1,
                     float* __restrict__ pacc){
  __shared__ float lh[64*64];
  int og = blockIdx.x, sj = blockIdx.y, b = blockIdx.z;
  int tid = threadIdx.x;
  for(int it=0; it<4; ++it){
    int f4 = tid + it*256;               // c*16 + s4
    int c = f4>>4, s4 = f4&15;
    float4 v = *(const float4*)(h + (size_t)(b*64+c)*SPc + sj*64 + s4*4);
    *(float4*)(&lh[c*64 + s4*4]) = v;
  }
  __syncthreads();
  int osub = tid>>6, s = tid&63;
  int ob = og*40 + osub*10;
  float acc[10];
  #pragma unroll
  for(int j=0;j<10;j++) acc[j] = bias[ob+j];
  for(int c=0;c<64;c++){
    float hv = lh[c*64+s];
    #pragma unroll
    for(int j=0;j<10;j++) acc[j] = fmaf(hv, w[(ob+j)*64 + c], acc[j]);
  }
  #pragma unroll
  for(int j=0;j<10;j++){
    int o = ob+j;
    t1[(size_t)(b*320+o)*SPc + sj*64 + s] = acc[j];
    float sm = acc[j], sq = acc[j]*acc[j];
    #pragma unroll
    for(int d=1; d<64; d<<=1){ sm += __shfl_xor(sm,d); sq += __shfl_xor(sq,d); }
    if(s==0){
      pacc[o*128 + b*64 + sj]         = sm;   // P=128
      pacc[40960 + o*128 + b*64 + sj] = sq;   // CP = 320*128
    }
  }
}

// ---- finalize (out-BN only): partials -> A,B ----
__global__ void k_fin(const float* __restrict__ pacc, int P, float invN,
                      const float* __restrict__ g, const float* __restrict__ bb,
                      float* __restrict__ A, float* __restrict__ B){
  __shared__ double sh[256], sh2[256];
  int c = blockIdx.x, C = gridDim.x, tid = threadIdx.x;
  double s=0.0, s2=0.0;
  for(int p=tid; p<P; p+=256){
    s  += (double)pacc[c*P+p];
    s2 += (double)pacc[C*P + c*P + p];
  }
  sh[tid]=s; sh2[tid]=s2; __syncthreads();
  for(int off=128; off>0; off>>=1){
    if(tid<off){ sh[tid]+=sh[tid+off]; sh2[tid]+=sh2[tid+off]; }
    __syncthreads();
  }
  if(tid==0){
    float m = (float)(sh[0]*(double)invN);
    float v = (float)(sh2[0]*(double)invN) - m*m;
    float r = rsqrtf(v + EPSc);
    float gc = g[c];
    A[c] = gc*r;
    B[c] = bb[c] - m*gc*r;
  }
}

// ---- depthwise 3x3; BN1 finalized in prologue; BN2 partials out ----
__global__ void k_dw_s(const float* __restrict__ t1, const float* __restrict__ w,
                       const float* __restrict__ bias, const float* __restrict__ g1,
                       const float* __restrict__ bb1, const float* __restrict__ ap,
                       const float* __restrict__ pin, float* __restrict__ t2,
                       float* __restrict__ pout){
  int tid = threadIdx.x;
  int idx = blockIdx.x*256 + tid;
  int q = idx&63, p=(idx>>6)&63, c=(idx>>12)%C5c, b=idx/(C5c*SPc);
  __shared__ float sAB[2];
  __shared__ float ws4[4];
  {
    float v = (tid<128) ? pin[c*128 + tid] : pin[40960 + c*128 + (tid-128)];
    #pragma unroll
    for(int d=1; d<64; d<<=1) v += __shfl_xor(v, d);
    int wv = tid>>6, ln = tid&63;
    if(ln==0) ws4[wv] = v;
    __syncthreads();
    if(tid==0){
      float S = ws4[0]+ws4[1], Q = ws4[2]+ws4[3];
      float m = S*(1.f/8192.f);
      float var = Q*(1.f/8192.f) - m*m;
      float r = rsqrtf(var + EPSc);
      float gc = g1[c];
      sAB[0] = gc*r; sAB[1] = bb1[c] - m*gc*r;
    }
    __syncthreads();
  }
  float a1 = sAB[0], b1 = sAB[1], al = ap[0];
  const float* ip = t1 + (size_t)(b*C5c+c)*SPc;
  const float* wp = w + c*9;
  float acc = bias[c];
  #pragma unroll
  for(int u=0; u<3; u++){
    int pp = p+u-1; if((unsigned)pp >= 64u) continue;
    #pragma unroll
    for(int v=0; v<3; v++){
      int qq = q+v-1; if((unsigned)qq >= 64u) continue;
      float y = fmaf(ip[pp*64+qq], a1, b1);
      y = y >= 0.f ? y : al*y;
      acc = fmaf(y, wp[u*3+v], acc);
    }
  }
  t2[idx] = acc;
  float sm = acc, sq = acc*acc;
  #pragma unroll
  for(int d=1; d<64; d<<=1){ sm += __shfl_xor(sm,d); sq += __shfl_xor(sq,d); }
  __shared__ float sred[8];
  int wv = tid>>6, ln = tid&63;
  if(ln==0){ sred[wv]=sm; sred[4+wv]=sq; }
  __syncthreads();
  if(tid==0){
    float S = ((sred[0]+sred[1])+(sred[2]+sred[3]));
    float Q = ((sred[4]+sred[5])+(sred[6]+sred[7]));
    int j = blockIdx.x & 15;
    pout[c*32 + b*16 + j]         = S;   // P=32
    pout[10240 + c*32 + b*16 + j] = Q;   // CP = 320*32
  }
}

// ---- full-K 1x1 conv 320->64; BN2 finalized in prologue; BN3 partials out ----
__global__ void k_c3f(const float* __restrict__ t2, const float* __restrict__ w,
                      const float* __restrict__ bias, const float* __restrict__ g2,
                      const float* __restrict__ bb2, const float* __restrict__ ap,
                      const float* __restrict__ pin, float* __restrict__ ts,
                      float* __restrict__ pout){
  __shared__ float sA[320], sB[320];
  __shared__ float li[320*16];    // 20 KB
  int sjf = blockIdx.x, b = blockIdx.y;
  int tid = threadIdx.x;
  for(int c = tid; c < 320; c += 256){
    const float4* ps = (const float4*)(pin + c*32);
    const float4* pq = (const float4*)(pin + 10240 + c*32);
    float S=0.f, Q=0.f;
    #pragma unroll
    for(int j=0;j<8;j++){ float4 a = ps[j]; S += ((a.x+a.y)+(a.z+a.w)); }
    #pragma unroll
    for(int j=0;j<8;j++){ float4 a = pq[j]; Q += ((a.x+a.y)+(a.z+a.w)); }
    float m = S*(1.f/8192.f);
    float var = Q*(1.f/8192.f) - m*m;
    float r = rsqrtf(var + EPSc);
    float gc = g2[c];
    sA[c] = gc*r; sB[c] = bb2[c] - m*gc*r;
  }
  __syncthreads();
  float al = ap[0];
  for(int t = tid; t < 1280; t += 256){
    int c = t>>2, k4 = t&3;
    float4 v = *(const float4*)(t2 + (size_t)(b*C5c+c)*SPc + sjf*16 + k4*4);
    float a1 = sA[c], b1 = sB[c];
    float4 y;
    y.x = fmaf(v.x, a1, b1); y.x = y.x>=0.f ? y.x : al*y.x;
    y.y = fmaf(v.y, a1, b1); y.y = y.y>=0.f ? y.y : al*y.y;
    y.z = fmaf(v.z, a1, b1); y.z = y.z>=0.f ? y.z : al*y.z;
    y.w = fmaf(v.w, a1, b1); y.w = y.w>=0.f ? y.w : al*y.w;
    *(float4*)(&li[c*16 + k4*4]) = y;
  }
  __syncthreads();
  int og = tid>>4, s = tid&15;
  float acc[4];
  #pragma unroll
  for(int j=0;j<4;j++) acc[j] = bias[og*4+j];
  const float* wb = w + (size_t)(og*4)*C5c;
  for(int c=0; c<320; c++){
    float hv = li[c*16 + s];
    #pragma unroll
    for(int j=0;j<4;j++)
      acc[j] = fmaf(hv, wb[j*C5c + c], acc[j]);
  }
  #pragma unroll
  for(int j=0;j<4;j++){
    int o = og*4+j;
    ts[(size_t)(b*64+o)*SPc + sjf*16 + s] = acc[j];
    float sm = acc[j], sq = acc[j]*acc[j];
    #pragma unroll
    for(int d=1; d<16; d<<=1){ sm += __shfl_xor(sm,d); sq += __shfl_xor(sq,d); }
    if(s==0){
      pout[o*512 + b*256 + sjf]         = sm;  // P=512
      pout[32768 + o*512 + b*256 + sjf] = sq;  // CP = 64*512
    }
  }
}

// ---- BN3 (finalized in prologue, P=512) + PReLU3 + residual add into h ----
__global__ void k_addres(const float* __restrict__ ts, float* __restrict__ h,
                         const float* __restrict__ g3, const float* __restrict__ bb3,
                         const float* __restrict__ ap, const float* __restrict__ pin){
  int tid = threadIdx.x;
  int idx = blockIdx.x*256 + tid;
  int c = (idx>>12)&63;              // constant per block
  __shared__ float sAB[2];
  __shared__ float w8[8];
  {
    float S = pin[c*512 + tid] + pin[c*512 + 256 + tid];
    float Q = pin[32768 + c*512 + tid] + pin[32768 + c*512 + 256 + tid];
    #pragma unroll
    for(int d=1; d<64; d<<=1){ S += __shfl_xor(S,d); Q += __shfl_xor(Q,d); }
    int wv = tid>>6, ln = tid&63;
    if(ln==0){ w8[wv] = S; w8[4+wv] = Q; }
    __syncthreads();
    if(tid==0){
      float Sa = (w8[0]+w8[1])+(w8[2]+w8[3]);
      float Qa = (w8[4]+w8[5])+(w8[6]+w8[7]);
      float m = Sa*(1.f/8192.f);
      float var = Qa*(1.f/8192.f) - m*m;
      float r = rsqrtf(var + EPSc);
      float gc = g3[c];
      sAB[0] = gc*r; sAB[1] = bb3[c] - m*gc*r;
    }
    __syncthreads();
  }
  float y = fmaf(ts[idx], sAB[0], sAB[1]);
  float al = ap[0];
  y = y >= 0.f ? y : al*y;
  h[idx] += y;
}

// ---- head v2: 1x1 conv (64->512) -> gvol [b][q][ci][k][o][z=p] ----
// block = (b, q, pgg of 8 rows): 1024 blocks, 256 thr.
// h-tile (8x64, pad65) staged once; weights chunked 64 rows (pad65).
// h read ONCE total (2 MB vs 512 MB before).
__global__ void k_head_t(const float* __restrict__ h, const float* __restrict__ w,
                         const float* __restrict__ bias, float* __restrict__ gv){
  __shared__ float lh[8*65];      // [p8][kc64]
  __shared__ float lw[64*65];     // [cc64][kc64]
  int bid = blockIdx.x;           // (b*64 + q)*8 + pgg
  int pgg = bid & 7, q = (bid>>3) & 63, b = bid >> 9;
  int tid = threadIdx.x;
  // stage h tile: 8 p-rows x 64 kc (scalar gather, 2/thread)
  for(int t = tid; t < 512; t += 256){
    int p = t >> 6, kc = t & 63;
    lh[p*65 + kc] = h[((size_t)(b*64+kc))*SPc + (pgg*8+p)*64 + q];
  }
  int cc = tid & 63, pp = tid >> 6;     // wave-uniform pp
  float* gb = gv + (size_t)b*(64*16*2048) + ((size_t)q*16)*2048;
  for(int ch = 0; ch < 8; ++ch){
    __syncthreads();                    // lw safe to overwrite (and lh ready at ch=0)
    for(int t = tid; t < 1024; t += 256){
      int rc = t >> 4, f4 = t & 15;
      int combo = ch*64 + rc;
      int ci = combo>>5, kk = (combo>>4)&1, o = combo&15;
      int c0 = (o*16+ci)*2 + kk;
      float4 v = *(const float4*)(w + (size_t)c0*64 + f4*4);
      *(float4*)(&lw[rc*65 + f4*4]) = v;
    }
    __syncthreads();
    int combo = ch*64 + cc;
    int ci = combo>>5, kk = (combo>>4)&1, o = combo&15;
    int c0 = (o*16+ci)*2 + kk;
    float a0 = 0.f, a1 = 0.f;
    const float* lh0 = &lh[(pp*2+0)*65];
    const float* lh1 = &lh[(pp*2+1)*65];
    const float* lwr = &lw[cc*65];
    #pragma unroll 8
    for(int kc=0; kc<64; kc++){
      float wv = lwr[kc];
      a0 = fmaf(lh0[kc], wv, a0);       // lh broadcast (free)
      a1 = fmaf(lh1[kc], wv, a1);       // lw bank = (lane+kc)%32 (conflict-free)
    }
    float bv = bias[c0];
    float* dst = gb + (size_t)ci*2048 + kk*1024 + o*64 + pgg*8 + pp*2;
    *(float2*)dst = make_float2(a0 + bv, a1 + bv);
  }
}

// ---- slice v5: 17-col segments, lane-transposed (16 lanes = 16 o, 1 px) ----
__global__ void k_slice(const float* __restrict__ x, const float* __restrict__ gv,
                        float* __restrict__ outp, float* __restrict__ pacc){
  __shared__ float lds[8320];     // 4160 float2
  int xseg = blockIdx.x, hp = blockIdx.y, b = blockIdx.z;
  int tid = threadIdx.x;
  const float* gb = gv + (size_t)b*(64*16*2048);
  int y0 = (hp*63)/255;
  int y1 = min(y0+1, 63);
  float fy = hp*(63.f/255.f) - (float)y0;

  if(tid < 128){
    int half = tid & 1, o = (tid>>1)&15, k = (tid>>5)&1, cix = (tid>>6)&1;
    int xs = min(xseg + cix, 15);
    const float* b0p = gb + (size_t)(y0*16+xs)*2048 + k*1024 + o*64;
    const float* b1p = gb + (size_t)(y1*16+xs)*2048 + k*1024 + o*64;
    float2* d = (float2*)lds + cix*2080 + k*1040 + o*65;
    float prev = 0.f;
    if(half){
      float a = b0p[31], c = b1p[31];
      prev = fmaf(fy, c-a, a);
    }
    int j0 = half*8;
    #pragma unroll
    for(int j=0; j<8; ++j){
      int jj = j0 + j;
      float4 a = *(const float4*)(b0p + jj*4);
      float4 c = *(const float4*)(b1p + jj*4);
      float v0 = fmaf(fy, c.x-a.x, a.x);
      float v1 = fmaf(fy, c.y-a.y, a.y);
      float v2 = fmaf(fy, c.z-a.z, a.z);
      float v3 = fmaf(fy, c.w-a.w, a.w);
      if(j > 0 || half) d[4*jj-1] = make_float2(prev, v0);
      d[4*jj]   = make_float2(v0, v1);
      d[4*jj+1] = make_float2(v1, v2);
      d[4*jj+2] = make_float2(v2, v3);
      prev = v3;
    }
    if(half) d[63] = make_float2(prev, prev);
  }
  __syncthreads();

  int wv = tid>>6, lane = tid&63;
  int o = lane & 15, pl = lane >> 4;  // 16 lanes = 16 o of ONE pixel
  int lc = wv*4 + pl;                 // 0..19 (17+ invalid)
  int wq = xseg*17 + lc;
  bool act = (lc < 17) && (wq < 256);
  int wqc = min(wq, 255);

  float fx = (float)lc * (1.f/17.f);
  float cwA = 1.f - fx, cwB = fx;
  int obase = o*65;
  const float2* l2 = (const float2*)lds;

  float acc = 0.f, bacc = 0.f;
  for(int i=0; i<CIc; i++){
    float xv = x[((size_t)(b*CIc+i)*Hc + hp)*Wc + wqc];
    float g = fminf(fmaxf(xv, 0.f), 1.f);
    float pz = g*63.f;
    int z0 = (int)pz; float fz = pz - (float)z0;
    float wz0 = cwA*(1.f-fz), wz1 = cwA*fz;
    float vz0 = cwB*(1.f-fz), vz1 = cwB*fz;
    int aA = obase + z0, aB = 2080 + obase + z0;
    float2 wA = l2[aA],        wB = l2[aB];
    float2 bA = l2[aA + 1040], bB = l2[aB + 1040];
    float wsum = fmaf(wz0, wA.x, fmaf(wz1, wA.y, fmaf(vz0, wB.x, vz1*wB.y)));
    float bsum = fmaf(wz0, bA.x, fmaf(wz1, bA.y, fmaf(vz0, bB.x, vz1*bB.y)));
    acc  = fmaf(xv, wsum, acc);
    bacc += bsum;
  }
  float vout = act ? (acc + bacc*(1.f/16.f)) : 0.f;
  if(act)
    outp[((size_t)(b*COc+o)*Hc + hp)*Wc + wq] = vout;

  float sm = vout, sq = vout*vout;
  sm += __shfl_xor(sm,16); sq += __shfl_xor(sq,16);
  sm += __shfl_xor(sm,32); sq += __shfl_xor(sq,32);
  __syncthreads();
  if(lane < 16){ lds[(wv*16+o)*2] = sm; lds[(wv*16+o)*2+1] = sq; }
  __syncthreads();
  if(tid < 32){
    int oo = tid>>1, kd = tid&1;
    float S = (((lds[(0*16+oo)*2+kd] + lds[(1*16+oo)*2+kd])
             +  (lds[(2*16+oo)*2+kd] + lds[(3*16+oo)*2+kd]))
             +   lds[(4*16+oo)*2+kd]);
    int blk = (b*256 + hp)*16 + xseg;       // P=8192
    pacc[kd*131072 + oo*8192 + blk] = S;    // CP = 16*8192
  }
}

// ---- final BN + SiLU in place on d_out ----
__global__ void k_final(float* __restrict__ out, const float* __restrict__ A,
                        const float* __restrict__ B){
  int idx = blockIdx.x*256 + threadIdx.x;
  int c = (idx>>16)&15;
  float y = fmaf(out[idx], A[c], B[c]);
  out[idx] = y / (1.f + expf(-y));
}

} // namespace

extern "C" void kernel_launch(void* const* d_in, const int* in_sizes, int n_in,
                              void* d_out, int out_size, void* d_ws, size_t ws_size,
                              hipStream_t stream){
  const float* x       = (const float*)d_in[0];
  const float* conv0_w = (const float*)d_in[1];
  const float* conv0_b = (const float*)d_in[2];
  const float* prelu0  = (const float*)d_in[3];
  const float* c1w  = (const float*)d_in[4];
  const float* c1b  = (const float*)d_in[5];
  const float* bn1g = (const float*)d_in[6];
  const float* bn1b = (const float*)d_in[7];
  const float* p1   = (const float*)d_in[8];
  const float* dww  = (const float*)d_in[9];
  const float* dwb  = (const float*)d_in[10];
  const float* bn2g = (const float*)d_in[11];
  const float* bn2b = (const float*)d_in[12];
  const float* p2   = (const float*)d_in[13];
  const float* c3w  = (const float*)d_in[14];
  const float* c3b  = (const float*)d_in[15];
  const float* bn3g = (const float*)d_in[16];
  const float* bn3b = (const float*)d_in[17];
  const float* p3   = (const float*)d_in[18];
  const float* hw   = (const float*)d_in[19];
  const float* hb   = (const float*)d_in[20];
  const float* obg  = (const float*)d_in[21];
  const float* obb  = (const float*)d_in[22];
  float* out = (float*)d_out;
  float* ws  = (float*)d_ws;

  // workspace (floats)
  float* xd    = ws;                 // 131072
  float* h     = xd + 131072;        // 524288
  float* A     = h  + 524288;        // 320
  float* B     = A  + 320;           // 320
  float* pacc  = B  + 320;           // 81920  BN1 partials
  float* paccb = pacc + 81920;       // 20480  BN2 partials
  float* paccc = paccb + 20480;      // 65536  BN3 partials
  float* t1    = paccc + 65536;      // 2621440
  float* t2    = t1 + 2621440;       // 2621440
  float* ts    = t2 + 2621440;       // 524288
  float* gv    = t1;                 // 4194304 aliases t1+t2 (dead by head)
  float* pacc2 = ts;                 // 262144 slice partials alias ts

  k_down <<<512,  256, 0, stream>>>(x, xd);
  k_conv0<<<2048, 256, 0, stream>>>(xd, conv0_w, conv0_b, prelu0, h);

  for(int i=0; i<3; i++){
    k_c1  <<<dim3(8,64,Bn), 256, 0, stream>>>(h, c1w + i*20480, c1b + i*320, t1, pacc);
    k_dw_s<<<10240, 256, 0, stream>>>(t1, dww + i*2880, dwb + i*320,
                                      bn1g+i*320, bn1b+i*320, p1+i, pacc, t2, paccb);
    k_c3f <<<dim3(256,Bn), 256, 0, stream>>>(t2, c3w + i*20480, c3b + i*64,
                                             bn2g+i*320, bn2b+i*320, p2+i, paccb, ts, paccc);
    k_addres<<<2048, 256, 0, stream>>>(ts, h, bn3g+i*64, bn3b+i*64, p3+i, paccc);
  }

  k_head_t<<<1024, 256, 0, stream>>>(h, hw, hb, gv);
  k_slice <<<dim3(16,256,Bn), 320, 0, stream>>>(x, gv, out, pacc2);
  k_fin   <<<16, 256, 0, stream>>>(pacc2, 8192, 1.f/131072.f, obg, obb, A, B);
  k_final <<<8192, 256, 0, stream>>>(out, A, B);
}